// Round 1
// baseline (1096.594 us; speedup 1.0000x reference)
//
#include <hip/hip_runtime.h>

// GCN: 3 layers, aggregate-then-transform (S x) W + b, head folded into W3@Wh.
// ws layout (floats): dinv[N] | a1[3N] | bufA[64N] | bufB[64N] | wc[65]
// deg-count (int) aliases bufB (dead before bufB first written).

__global__ void count_deg(const int* __restrict__ dst, int* __restrict__ cnt, int E) {
    int e = blockIdx.x * blockDim.x + threadIdx.x;
    if (e < E) atomicAdd(&cnt[dst[e]], 1);
}

__global__ void compute_dinv(const int* __restrict__ cnt, float* __restrict__ dinv, int N) {
    int n = blockIdx.x * blockDim.x + threadIdx.x;
    if (n < N) dinv[n] = rsqrtf((float)(cnt[n] + 1));   // +1 self-loop; deg>=1 always
}

__global__ void agg3_self(const float* __restrict__ x, const float* __restrict__ dinv,
                          float* __restrict__ a1, int N) {
    int n = blockIdx.x * blockDim.x + threadIdx.x;
    if (n >= N) return;
    float d = dinv[n], s = d * d;
    a1[n*3+0] = s * x[n*3+0];
    a1[n*3+1] = s * x[n*3+1];
    a1[n*3+2] = s * x[n*3+2];
}

__global__ void agg3_edge(const float* __restrict__ x, const int* __restrict__ src,
                          const int* __restrict__ dst, const float* __restrict__ dinv,
                          float* __restrict__ a1, int E) {
    int e = blockIdx.x * blockDim.x + threadIdx.x;
    if (e >= E) return;
    int s = src[e], d = dst[e];
    float w = dinv[s] * dinv[d];
    atomicAdd(&a1[d*3+0], w * x[s*3+0]);
    atomicAdd(&a1[d*3+1], w * x[s*3+1]);
    atomicAdd(&a1[d*3+2], w * x[s*3+2]);
}

// h1[n][f] = relu(sum_k a1[n][k] * W1[k][f] + b1[f]),  K=3
__global__ void mm3_relu(const float* __restrict__ a1, const float* __restrict__ W1,
                         const float* __restrict__ b1, float* __restrict__ h1, int N) {
    int t = blockIdx.x * blockDim.x + threadIdx.x;
    int n = t >> 6, f = t & 63;
    if (n >= N) return;
    float acc = b1[f];
    acc += a1[n*3+0] * W1[0*64+f];
    acc += a1[n*3+1] * W1[1*64+f];
    acc += a1[n*3+2] * W1[2*64+f];
    h1[n*64+f] = fmaxf(acc, 0.0f);
}

// out[n][f] = dinv[n]^2 * h[n][f]   (self-loop term; full overwrite = init)
__global__ void self64(const float* __restrict__ h, const float* __restrict__ dinv,
                       float* __restrict__ out, int N) {
    int t = blockIdx.x * blockDim.x + threadIdx.x;
    int n = t >> 6, f = t & 63;
    if (n >= N) return;
    float d = dinv[n];
    out[n*64+f] = d * d * h[n*64+f];
}

// one wave per edge, lane = feature: out[dst][lane] += dinv[s]*dinv[d]*h[src][lane]
__global__ void scatter64(const float* __restrict__ h, const int* __restrict__ src,
                          const int* __restrict__ dst, const float* __restrict__ dinv,
                          float* __restrict__ out, int E) {
    int wid  = (blockIdx.x * blockDim.x + threadIdx.x) >> 6;
    int lane = threadIdx.x & 63;
    int nwaves = (gridDim.x * blockDim.x) >> 6;
    for (int e = wid; e < E; e += nwaves) {
        int s = src[e], d = dst[e];
        float w = dinv[s] * dinv[d];
        atomicAdd(&out[d*64 + lane], w * h[s*64 + lane]);
    }
}

// out[n][f] = relu?(sum_k A[n][k]*W[k][f] + b[f]); W staged in LDS, 32 nodes/block
__global__ void mm64(const float* __restrict__ A, const float* __restrict__ W,
                     const float* __restrict__ b, float* __restrict__ out,
                     int N, int do_relu) {
    __shared__ float Wl[64*64];
    __shared__ float bl[64];
    int tid = threadIdx.x;            // 256
    for (int i = tid; i < 4096; i += 256) Wl[i] = W[i];
    if (tid < 64) bl[tid] = b[tid];
    __syncthreads();
    const int f = tid & 63;
    const int g = tid >> 6;           // 0..3 (wave id)
    const int NPT = 8;                // nodes per thread
    int base = blockIdx.x * (4 * NPT);
    const float4* A4 = (const float4*)A;
    #pragma unroll
    for (int i = 0; i < NPT; i++) {
        int n = base + g + 4*i;
        if (n >= N) continue;
        float acc = bl[f];
        #pragma unroll
        for (int k4 = 0; k4 < 16; k4++) {
            float4 a = A4[n*16 + k4];           // wave-uniform -> broadcast load
            acc += a.x * Wl[(4*k4+0)*64 + f];
            acc += a.y * Wl[(4*k4+1)*64 + f];
            acc += a.z * Wl[(4*k4+2)*64 + f];
            acc += a.w * Wl[(4*k4+3)*64 + f];
        }
        if (do_relu) acc = fmaxf(acc, 0.0f);
        out[n*64 + f] = acc;
    }
}

// wc[k] = sum_f W3[k][f]*Wh[f];  wc[64] = sum_f b3[f]*Wh[f] + bh
__global__ void fold_head(const float* __restrict__ W3, const float* __restrict__ b3,
                          const float* __restrict__ Wh, const float* __restrict__ bh,
                          float* __restrict__ wc) {
    int k = threadIdx.x;              // 64 threads
    float acc = 0.0f;
    for (int f = 0; f < 64; f++) acc += W3[k*64+f] * Wh[f];
    wc[k] = acc;
    if (k == 0) {
        float bb = bh[0];
        for (int f = 0; f < 64; f++) bb += b3[f] * Wh[f];
        wc[64] = bb;
    }
}

// logits[n] = sum_k a3[n][k]*wc[k] + wc[64]; wave per node, shuffle reduce
__global__ void final_dot(const float* __restrict__ a3, const float* __restrict__ wc,
                          float* __restrict__ out, int N) {
    int t = blockIdx.x * blockDim.x + threadIdx.x;
    int n = t >> 6, lane = t & 63;
    if (n >= N) return;
    float v = a3[n*64 + lane] * wc[lane];
    for (int off = 32; off; off >>= 1) v += __shfl_down(v, off);
    if (lane == 0) out[n] = v + wc[64];
}

extern "C" void kernel_launch(void* const* d_in, const int* in_sizes, int n_in,
                              void* d_out, int out_size, void* d_ws, size_t ws_size,
                              hipStream_t stream) {
    const float* x   = (const float*)d_in[0];
    const int*   ei  = (const int*)d_in[1];
    const float* W1  = (const float*)d_in[2];
    const float* b1  = (const float*)d_in[3];
    const float* W2  = (const float*)d_in[4];
    const float* b2  = (const float*)d_in[5];
    const float* W3  = (const float*)d_in[6];
    const float* b3  = (const float*)d_in[7];
    const float* Wh  = (const float*)d_in[8];
    const float* bh  = (const float*)d_in[9];
    float* logits = (float*)d_out;

    const int N = in_sizes[0] / 3;
    const int E = in_sizes[1] / 2;
    const int* src = ei;
    const int* dst = ei + E;

    float* base = (float*)d_ws;
    float* dinv = base;                  // N
    float* a1   = base + (size_t)N;      // 3N
    float* bufA = base + (size_t)4*N;    // 64N
    float* bufB = base + (size_t)68*N;   // 64N
    float* wc   = base + (size_t)132*N;  // 65
    int*   cnt  = (int*)bufB;            // aliases bufB (dead before bufB written)

    const int BS = 256;
    int gE  = (E + BS - 1) / BS;
    int gN  = (N + BS - 1) / BS;
    int gNF = (N * 64 + BS - 1) / BS;    // thread per (node,feat)
    int gMM = (N + 31) / 32;             // 32 nodes per block
    int gSC = 8192;                      // grid-stride waves over edges

    hipMemsetAsync(cnt, 0, (size_t)N * sizeof(int), stream);
    count_deg   <<<gE,  BS, 0, stream>>>(dst, cnt, E);
    compute_dinv<<<gN,  BS, 0, stream>>>(cnt, dinv, N);

    // ---- layer 1 (aggregate 3 feats, then transform) ----
    agg3_self   <<<gN,  BS, 0, stream>>>(x, dinv, a1, N);
    agg3_edge   <<<gE,  BS, 0, stream>>>(x, src, dst, dinv, a1, E);
    mm3_relu    <<<gNF, BS, 0, stream>>>(a1, W1, b1, bufA, N);      // bufA = h1

    // ---- layer 2 ----
    self64      <<<gNF, BS, 0, stream>>>(bufA, dinv, bufB, N);      // bufB = self part
    scatter64   <<<gSC, BS, 0, stream>>>(bufA, src, dst, dinv, bufB, E); // bufB = a2
    mm64        <<<gMM, BS, 0, stream>>>(bufB, W2, b2, bufA, N, 1); // bufA = h2

    // ---- layer 3 aggregation ----
    self64      <<<gNF, BS, 0, stream>>>(bufA, dinv, bufB, N);
    scatter64   <<<gSC, BS, 0, stream>>>(bufA, src, dst, dinv, bufB, E); // bufB = a3

    // ---- folded head ----
    fold_head   <<<1, 64, 0, stream>>>(W3, b3, Wh, bh, wc);
    final_dot   <<<gNF, BS, 0, stream>>>(bufB, wc, logits, N);
}

// Round 2
// 454.624 us; speedup vs baseline: 2.4121x; 2.4121x over previous
//
#include <hip/hip_runtime.h>

// GCN: 3 layers, aggregate-then-transform (S x) W + b, head folded into W3@Wh.
// R2: CSR (grouped-by-dst) gather aggregation replaces scatter-atomics.
// ws floats: dinv[N] | a1[3N] | bufA[64N] | bufB[64N] | rowptr[N+1] | bsums[1024] | ew[2E] | wc[65]
// cnt (int[N]) aliases bufA[0..N); fill (int[N]) aliases bufA[N..2N) — both dead before bufA written.

__global__ void count_deg(const int* __restrict__ dst, int* __restrict__ cnt, int E) {
    int e = blockIdx.x * blockDim.x + threadIdx.x;
    if (e < E) atomicAdd(&cnt[dst[e]], 1);
}

__global__ void compute_dinv(const int* __restrict__ cnt, float* __restrict__ dinv, int N) {
    int n = blockIdx.x * blockDim.x + threadIdx.x;
    if (n < N) dinv[n] = rsqrtf((float)(cnt[n] + 1));   // +1 self-loop
}

// ---- exclusive scan of cnt -> rowptr (3-phase, 256/block) ----
__global__ void scan1(const int* __restrict__ cnt, int* __restrict__ rowptr,
                      int* __restrict__ bsums, int N) {
    __shared__ int tmp[256];
    int i = blockIdx.x * 256 + threadIdx.x;
    int v = (i < N) ? cnt[i] : 0;
    tmp[threadIdx.x] = v; __syncthreads();
    for (int off = 1; off < 256; off <<= 1) {
        int t = (threadIdx.x >= off) ? tmp[threadIdx.x - off] : 0;
        __syncthreads();
        tmp[threadIdx.x] += t;
        __syncthreads();
    }
    if (i < N) rowptr[i] = tmp[threadIdx.x] - v;            // exclusive within block
    if (threadIdx.x == 255) bsums[blockIdx.x] = tmp[255];   // block total
}

__global__ void scan2(int* __restrict__ bsums, int nb) {    // single block, 1024 thr
    __shared__ int tmp[1024];
    int v = (threadIdx.x < nb) ? bsums[threadIdx.x] : 0;
    tmp[threadIdx.x] = v; __syncthreads();
    for (int off = 1; off < 1024; off <<= 1) {
        int t = (threadIdx.x >= off) ? tmp[threadIdx.x - off] : 0;
        __syncthreads();
        tmp[threadIdx.x] += t;
        __syncthreads();
    }
    if (threadIdx.x < nb) bsums[threadIdx.x] = tmp[threadIdx.x] - v;  // exclusive
}

__global__ void scan3(int* __restrict__ rowptr, const int* __restrict__ bsums, int N, int E) {
    int i = blockIdx.x * 256 + threadIdx.x;
    if (i < N) rowptr[i] += bsums[blockIdx.x];
    if (i == 0) rowptr[N] = E;
}

// slot edges into CSR: ew[p] = {src_as_float, dinv[s]*dinv[d]}
__global__ void csr_fill(const int* __restrict__ src, const int* __restrict__ dst,
                         const float* __restrict__ dinv, const int* __restrict__ rowptr,
                         int* __restrict__ fill, float2* __restrict__ ew, int E) {
    int e = blockIdx.x * blockDim.x + threadIdx.x;
    if (e >= E) return;
    int s = src[e], d = dst[e];
    int p = rowptr[d] + atomicAdd(&fill[d], 1);
    ew[p] = make_float2(__int_as_float(s), dinv[s] * dinv[d]);
}

// layer-1 aggregation over 3 input feats, thread per node
__global__ void agg3_csr(const float* __restrict__ x, const float2* __restrict__ ew,
                         const int* __restrict__ rowptr, const float* __restrict__ dinv,
                         float* __restrict__ a1, int N) {
    int n = blockIdx.x * blockDim.x + threadIdx.x;
    if (n >= N) return;
    float dv = dinv[n], sw = dv * dv;
    float a0 = sw * x[n*3+0], a1v = sw * x[n*3+1], a2 = sw * x[n*3+2];
    int end = rowptr[n+1];
    for (int p = rowptr[n]; p < end; ++p) {
        float2 e = ew[p];
        int s = __float_as_int(e.x);
        float w = e.y;
        a0  += w * x[s*3+0];
        a1v += w * x[s*3+1];
        a2  += w * x[s*3+2];
    }
    a1[n*3+0] = a0; a1[n*3+1] = a1v; a1[n*3+2] = a2;
}

// h1[n][f] = relu(a1[n][:3] @ W1 + b1)
__global__ void mm3_relu(const float* __restrict__ a1, const float* __restrict__ W1,
                         const float* __restrict__ b1, float* __restrict__ h1, int N) {
    int t = blockIdx.x * blockDim.x + threadIdx.x;
    int n = t >> 6, f = t & 63;
    if (n >= N) return;
    float acc = b1[f];
    acc += a1[n*3+0] * W1[0*64+f];
    acc += a1[n*3+1] * W1[1*64+f];
    acc += a1[n*3+2] * W1[2*64+f];
    h1[n*64+f] = fmaxf(acc, 0.0f);
}

// wave per dst node, lane = feature; self-loop init + serial neighbor gather
__global__ void agg64_csr(const float* __restrict__ h, const float2* __restrict__ ew,
                          const int* __restrict__ rowptr, const float* __restrict__ dinv,
                          float* __restrict__ out, int N) {
    int wid  = (blockIdx.x * blockDim.x + threadIdx.x) >> 6;
    int lane = threadIdx.x & 63;
    if (wid >= N) return;
    float dv = dinv[wid];
    float acc = dv * dv * h[wid*64 + lane];
    int p = rowptr[wid], end = rowptr[wid+1];
    // unroll by 2: two gathers in flight
    for (; p + 1 < end; p += 2) {
        float2 e0 = ew[p], e1 = ew[p+1];
        int s0 = __float_as_int(e0.x), s1 = __float_as_int(e1.x);
        float v0 = h[s0*64 + lane], v1 = h[s1*64 + lane];
        acc += e0.y * v0;
        acc += e1.y * v1;
    }
    if (p < end) {
        float2 e0 = ew[p];
        acc += e0.y * h[__float_as_int(e0.x)*64 + lane];
    }
    out[wid*64 + lane] = acc;
}

// out[n][f] = relu?(A[n][:64] @ W + b); W staged in LDS, 32 nodes/block
__global__ void mm64(const float* __restrict__ A, const float* __restrict__ W,
                     const float* __restrict__ b, float* __restrict__ out,
                     int N, int do_relu) {
    __shared__ float Wl[64*64];
    __shared__ float bl[64];
    int tid = threadIdx.x;            // 256
    for (int i = tid; i < 4096; i += 256) Wl[i] = W[i];
    if (tid < 64) bl[tid] = b[tid];
    __syncthreads();
    const int f = tid & 63;
    const int g = tid >> 6;
    const int NPT = 8;
    int base = blockIdx.x * (4 * NPT);
    const float4* A4 = (const float4*)A;
    #pragma unroll
    for (int i = 0; i < NPT; i++) {
        int n = base + g + 4*i;
        if (n >= N) continue;
        float acc = bl[f];
        #pragma unroll
        for (int k4 = 0; k4 < 16; k4++) {
            float4 a = A4[n*16 + k4];
            acc += a.x * Wl[(4*k4+0)*64 + f];
            acc += a.y * Wl[(4*k4+1)*64 + f];
            acc += a.z * Wl[(4*k4+2)*64 + f];
            acc += a.w * Wl[(4*k4+3)*64 + f];
        }
        if (do_relu) acc = fmaxf(acc, 0.0f);
        out[n*64 + f] = acc;
    }
}

// wc[k] = W3[k][:] @ Wh; wc[64] = b3 @ Wh + bh
__global__ void fold_head(const float* __restrict__ W3, const float* __restrict__ b3,
                          const float* __restrict__ Wh, const float* __restrict__ bh,
                          float* __restrict__ wc) {
    int k = threadIdx.x;              // 64
    float acc = 0.0f;
    for (int f = 0; f < 64; f++) acc += W3[k*64+f] * Wh[f];
    wc[k] = acc;
    if (k == 0) {
        float bb = bh[0];
        for (int f = 0; f < 64; f++) bb += b3[f] * Wh[f];
        wc[64] = bb;
    }
}

// logits[n] = a3[n][:] @ wc[:64] + wc[64]; wave per node, shuffle reduce
__global__ void final_dot(const float* __restrict__ a3, const float* __restrict__ wc,
                          float* __restrict__ out, int N) {
    int t = blockIdx.x * blockDim.x + threadIdx.x;
    int n = t >> 6, lane = t & 63;
    if (n >= N) return;
    float v = a3[n*64 + lane] * wc[lane];
    for (int off = 32; off; off >>= 1) v += __shfl_down(v, off);
    if (lane == 0) out[n] = v + wc[64];
}

extern "C" void kernel_launch(void* const* d_in, const int* in_sizes, int n_in,
                              void* d_out, int out_size, void* d_ws, size_t ws_size,
                              hipStream_t stream) {
    const float* x   = (const float*)d_in[0];
    const int*   ei  = (const int*)d_in[1];
    const float* W1  = (const float*)d_in[2];
    const float* b1  = (const float*)d_in[3];
    const float* W2  = (const float*)d_in[4];
    const float* b2  = (const float*)d_in[5];
    const float* W3  = (const float*)d_in[6];
    const float* b3  = (const float*)d_in[7];
    const float* Wh  = (const float*)d_in[8];
    const float* bh  = (const float*)d_in[9];
    float* logits = (float*)d_out;

    const int N = in_sizes[0] / 3;
    const int E = in_sizes[1] / 2;
    const int* src = ei;
    const int* dst = ei + E;

    float* base = (float*)d_ws;
    size_t o = 0;
    float*  dinv   = base + o; o += (size_t)N;
    float*  a1     = base + o; o += (size_t)3*N;
    float*  bufA   = base + o; o += (size_t)64*N;
    float*  bufB   = base + o; o += (size_t)64*N;
    int*    rowptr = (int*)(base + o); o += (size_t)N + 1;
    int*    bsums  = (int*)(base + o); o += 1024;
    o = (o + 1) & ~(size_t)1;                      // 8B-align ew
    float2* ew     = (float2*)(base + o); o += (size_t)2*E;
    float*  wc     = base + o; o += 65;
    int* cnt  = (int*)bufA;          // dead before bufA written
    int* fill = (int*)bufA + N;

    const int BS = 256;
    int gE   = (E + BS - 1) / BS;
    int gN   = (N + BS - 1) / BS;        // also the scan grid (256/block)
    int gNF  = (N * 64 + BS - 1) / BS;
    int gMM  = (N + 31) / 32;
    int gAGG = (N + 3) / 4;              // 4 waves (nodes) per block

    hipMemsetAsync(cnt,  0, (size_t)N * sizeof(int), stream);
    hipMemsetAsync(fill, 0, (size_t)N * sizeof(int), stream);

    count_deg   <<<gE, BS, 0, stream>>>(dst, cnt, E);
    compute_dinv<<<gN, BS, 0, stream>>>(cnt, dinv, N);
    scan1       <<<gN, BS, 0, stream>>>(cnt, rowptr, bsums, N);
    scan2       <<<1, 1024, 0, stream>>>(bsums, gN);
    scan3       <<<gN, BS, 0, stream>>>(rowptr, bsums, N, E);
    csr_fill    <<<gE, BS, 0, stream>>>(src, dst, dinv, rowptr, fill, ew, E);

    // ---- layer 1 ----
    agg3_csr    <<<gN,  BS, 0, stream>>>(x, ew, rowptr, dinv, a1, N);
    mm3_relu    <<<gNF, BS, 0, stream>>>(a1, W1, b1, bufA, N);       // bufA = h1

    // ---- layer 2 ----
    agg64_csr   <<<gAGG, BS, 0, stream>>>(bufA, ew, rowptr, dinv, bufB, N);
    mm64        <<<gMM,  BS, 0, stream>>>(bufB, W2, b2, bufA, N, 1); // bufA = h2

    // ---- layer 3 aggregation + folded head ----
    agg64_csr   <<<gAGG, BS, 0, stream>>>(bufA, ew, rowptr, dinv, bufB, N);
    fold_head   <<<1, 64, 0, stream>>>(W3, b3, Wh, bh, wc);
    final_dot   <<<gNF, BS, 0, stream>>>(bufB, wc, logits, N);
}

// Round 3
// 357.413 us; speedup vs baseline: 3.0681x; 1.2720x over previous
//
#include <hip/hip_runtime.h>

// GCN: 3 layers. R3 restructure:
//  - a1 = S x (3-wide CSR gather), stored as float4 {a0,a1,a2,dinv^2}
//  - a2 = S relu(a1@W1+b1) with h1 recomputed per edge (16B uniform gather, L2-resident)
//  - z  = relu(a2@W2+b2) @ (W3@Wh)  (scalar per node, fused into mm64 epilogue)
//  - logits = S z + (b3@Wh+bh)      (4B scalar gather)
// ws floats: dinv[N] | a1(float4)[4N] | bufB[64N] | rowptr[N+1] | bsums[1024] | ew[2E] | z[N] | wc[65]
// cnt/fill (int[N] each) alias bufB — dead before bufB written.

__global__ void count_deg(const int* __restrict__ dst, int* __restrict__ cnt, int E) {
    int e = blockIdx.x * blockDim.x + threadIdx.x;
    if (e < E) atomicAdd(&cnt[dst[e]], 1);
}

__global__ void compute_dinv(const int* __restrict__ cnt, float* __restrict__ dinv, int N) {
    int n = blockIdx.x * blockDim.x + threadIdx.x;
    if (n < N) dinv[n] = rsqrtf((float)(cnt[n] + 1));   // +1 self-loop
}

// ---- exclusive scan of cnt -> rowptr ----
__global__ void scan1(const int* __restrict__ cnt, int* __restrict__ rowptr,
                      int* __restrict__ bsums, int N) {
    __shared__ int tmp[256];
    int i = blockIdx.x * 256 + threadIdx.x;
    int v = (i < N) ? cnt[i] : 0;
    tmp[threadIdx.x] = v; __syncthreads();
    for (int off = 1; off < 256; off <<= 1) {
        int t = (threadIdx.x >= off) ? tmp[threadIdx.x - off] : 0;
        __syncthreads();
        tmp[threadIdx.x] += t;
        __syncthreads();
    }
    if (i < N) rowptr[i] = tmp[threadIdx.x] - v;
    if (threadIdx.x == 255) bsums[blockIdx.x] = tmp[255];
}

__global__ void scan2(int* __restrict__ bsums, int nb) {    // 1 block, 1024 thr
    __shared__ int tmp[1024];
    int v = (threadIdx.x < nb) ? bsums[threadIdx.x] : 0;
    tmp[threadIdx.x] = v; __syncthreads();
    for (int off = 1; off < 1024; off <<= 1) {
        int t = (threadIdx.x >= off) ? tmp[threadIdx.x - off] : 0;
        __syncthreads();
        tmp[threadIdx.x] += t;
        __syncthreads();
    }
    if (threadIdx.x < nb) bsums[threadIdx.x] = tmp[threadIdx.x] - v;
}

__global__ void scan3(int* __restrict__ rowptr, const int* __restrict__ bsums, int N, int E) {
    int i = blockIdx.x * 256 + threadIdx.x;
    if (i < N) rowptr[i] += bsums[blockIdx.x];
    if (i == 0) rowptr[N] = E;
}

__global__ void csr_fill(const int* __restrict__ src, const int* __restrict__ dst,
                         const float* __restrict__ dinv, const int* __restrict__ rowptr,
                         int* __restrict__ fill, float2* __restrict__ ew, int E) {
    int e = blockIdx.x * blockDim.x + threadIdx.x;
    if (e >= E) return;
    int s = src[e], d = dst[e];
    int p = rowptr[d] + atomicAdd(&fill[d], 1);
    ew[p] = make_float2(__int_as_float(s), dinv[s] * dinv[d]);
}

// a1[n] = {S x}[n] (3-wide), .w = dinv[n]^2; thread per node
__global__ void agg3_csr(const float* __restrict__ x, const float2* __restrict__ ew,
                         const int* __restrict__ rowptr, const float* __restrict__ dinv,
                         float4* __restrict__ a1, int N) {
    int n = blockIdx.x * blockDim.x + threadIdx.x;
    if (n >= N) return;
    float dv = dinv[n], sw = dv * dv;
    float a0 = sw * x[n*3+0], a1v = sw * x[n*3+1], a2 = sw * x[n*3+2];
    int end = rowptr[n+1];
    for (int p = rowptr[n]; p < end; ++p) {
        float2 e = ew[p];
        int s = __float_as_int(e.x);
        float w = e.y;
        a0  += w * x[s*3+0];
        a1v += w * x[s*3+1];
        a2  += w * x[s*3+2];
    }
    a1[n] = make_float4(a0, a1v, a2, sw);
}

// a2[n][f] = a1[n].w * relu(a1[n]@W1[:,f]+b1[f]) + sum_e w * relu(a1[s]@W1[:,f]+b1[f])
// wave per node, lane = feature
__global__ void agg64_recompute(const float4* __restrict__ a1, const float2* __restrict__ ew,
                                const int* __restrict__ rowptr, const float* __restrict__ W1,
                                const float* __restrict__ b1, float* __restrict__ out, int N) {
    int wid  = (blockIdx.x * blockDim.x + threadIdx.x) >> 6;
    int lane = threadIdx.x & 63;
    if (wid >= N) return;
    float w0 = W1[0*64 + lane], w1 = W1[1*64 + lane], w2 = W1[2*64 + lane], bf = b1[lane];
    float4 an = a1[wid];
    float t = fmaf(an.x, w0, bf); t = fmaf(an.y, w1, t); t = fmaf(an.z, w2, t);
    float acc = an.w * fmaxf(t, 0.0f);
    int p = rowptr[wid], end = rowptr[wid+1];
    for (; p + 1 < end; p += 2) {
        float2 e0 = ew[p], e1 = ew[p+1];
        float4 s0 = a1[__float_as_int(e0.x)];
        float4 s1 = a1[__float_as_int(e1.x)];
        float t0 = fmaf(s0.x, w0, bf); t0 = fmaf(s0.y, w1, t0); t0 = fmaf(s0.z, w2, t0);
        float t1 = fmaf(s1.x, w0, bf); t1 = fmaf(s1.y, w1, t1); t1 = fmaf(s1.z, w2, t1);
        acc = fmaf(e0.y, fmaxf(t0, 0.0f), acc);
        acc = fmaf(e1.y, fmaxf(t1, 0.0f), acc);
    }
    if (p < end) {
        float2 e0 = ew[p];
        float4 s0 = a1[__float_as_int(e0.x)];
        float t0 = fmaf(s0.x, w0, bf); t0 = fmaf(s0.y, w1, t0); t0 = fmaf(s0.z, w2, t0);
        acc = fmaf(e0.y, fmaxf(t0, 0.0f), acc);
    }
    out[wid*64 + lane] = acc;
}

// wc[k] = W3[k][:] @ Wh; wc[64] = b3 @ Wh + bh
__global__ void fold_head(const float* __restrict__ W3, const float* __restrict__ b3,
                          const float* __restrict__ Wh, const float* __restrict__ bh,
                          float* __restrict__ wc) {
    int k = threadIdx.x;              // 64
    float acc = 0.0f;
    for (int f = 0; f < 64; f++) acc += W3[k*64+f] * Wh[f];
    wc[k] = acc;
    if (k == 0) {
        float bb = bh[0];
        for (int f = 0; f < 64; f++) bb += b3[f] * Wh[f];
        wc[64] = bb;
    }
}

// z[n] = relu(A[n][:64] @ W2 + b2) @ wc ; W2 in LDS, 32 nodes/block, wave holds a node
__global__ void mm64_fused_z(const float* __restrict__ A, const float* __restrict__ W,
                             const float* __restrict__ b, const float* __restrict__ wc,
                             float* __restrict__ z, int N) {
    __shared__ float Wl[64*64];
    __shared__ float bl[64];
    int tid = threadIdx.x;            // 256
    for (int i = tid; i < 4096; i += 256) Wl[i] = W[i];
    if (tid < 64) bl[tid] = b[tid];
    __syncthreads();
    const int f = tid & 63;
    const int g = tid >> 6;
    const float wcf = wc[f];
    const int NPT = 8;
    int base = blockIdx.x * (4 * NPT);
    const float4* A4 = (const float4*)A;
    #pragma unroll
    for (int i = 0; i < NPT; i++) {
        int n = base + g + 4*i;
        if (n >= N) continue;
        float acc = bl[f];
        #pragma unroll
        for (int k4 = 0; k4 < 16; k4++) {
            float4 a = A4[n*16 + k4];
            acc += a.x * Wl[(4*k4+0)*64 + f];
            acc += a.y * Wl[(4*k4+1)*64 + f];
            acc += a.z * Wl[(4*k4+2)*64 + f];
            acc += a.w * Wl[(4*k4+3)*64 + f];
        }
        float v = fmaxf(acc, 0.0f) * wcf;       // h2[n][f] * wc[f]
        for (int off = 32; off; off >>= 1) v += __shfl_down(v, off);
        if (f == 0) z[n] = v;
    }
}

// logits[n] = dinv[n]^2 * z[n] + sum_e w * z[s] + c; thread per node (z is L2-resident)
__global__ void agg_scalar(const float* __restrict__ z, const float2* __restrict__ ew,
                           const int* __restrict__ rowptr, const float* __restrict__ dinv,
                           const float* __restrict__ wc, float* __restrict__ out, int N) {
    int n = blockIdx.x * blockDim.x + threadIdx.x;
    if (n >= N) return;
    float dv = dinv[n];
    float acc = dv * dv * z[n];
    int end = rowptr[n+1];
    for (int p = rowptr[n]; p < end; ++p) {
        float2 e = ew[p];
        acc = fmaf(e.y, z[__float_as_int(e.x)], acc);
    }
    out[n] = acc + wc[64];
}

extern "C" void kernel_launch(void* const* d_in, const int* in_sizes, int n_in,
                              void* d_out, int out_size, void* d_ws, size_t ws_size,
                              hipStream_t stream) {
    const float* x   = (const float*)d_in[0];
    const int*   ei  = (const int*)d_in[1];
    const float* W1  = (const float*)d_in[2];
    const float* b1  = (const float*)d_in[3];
    const float* W2  = (const float*)d_in[4];
    const float* b2  = (const float*)d_in[5];
    const float* W3  = (const float*)d_in[6];
    const float* b3  = (const float*)d_in[7];
    const float* Wh  = (const float*)d_in[8];
    const float* bh  = (const float*)d_in[9];
    float* logits = (float*)d_out;

    const int N = in_sizes[0] / 3;
    const int E = in_sizes[1] / 2;
    const int* src = ei;
    const int* dst = ei + E;

    float* base = (float*)d_ws;
    size_t o = 0;
    float*  dinv   = base + o; o += (size_t)N;
    o = (o + 3) & ~(size_t)3;                      // 16B-align a1
    float4* a1     = (float4*)(base + o); o += (size_t)4*N;
    float*  bufB   = base + o; o += (size_t)64*N;
    int*    rowptr = (int*)(base + o); o += (size_t)N + 1;
    int*    bsums  = (int*)(base + o); o += 1024;
    o = (o + 1) & ~(size_t)1;                      // 8B-align ew
    float2* ew     = (float2*)(base + o); o += (size_t)2*E;
    float*  zbuf   = base + o; o += (size_t)N;
    float*  wc     = base + o; o += 65;
    int* cnt  = (int*)bufB;          // dead before bufB written
    int* fill = (int*)bufB + N;

    const int BS = 256;
    int gE   = (E + BS - 1) / BS;
    int gN   = (N + BS - 1) / BS;
    int gMM  = (N + 31) / 32;
    int gAGG = (N + 3) / 4;              // 4 waves per block

    hipMemsetAsync(cnt,  0, (size_t)N * sizeof(int), stream);
    hipMemsetAsync(fill, 0, (size_t)N * sizeof(int), stream);

    count_deg   <<<gE, BS, 0, stream>>>(dst, cnt, E);
    compute_dinv<<<gN, BS, 0, stream>>>(cnt, dinv, N);
    scan1       <<<gN, BS, 0, stream>>>(cnt, rowptr, bsums, N);
    scan2       <<<1, 1024, 0, stream>>>(bsums, gN);
    scan3       <<<gN, BS, 0, stream>>>(rowptr, bsums, N, E);
    csr_fill    <<<gE, BS, 0, stream>>>(src, dst, dinv, rowptr, fill, ew, E);

    agg3_csr        <<<gN,   BS, 0, stream>>>(x, ew, rowptr, dinv, a1, N);
    agg64_recompute <<<gAGG, BS, 0, stream>>>(a1, ew, rowptr, W1, b1, bufB, N);
    fold_head       <<<1, 64, 0, stream>>>(W3, b3, Wh, bh, wc);
    mm64_fused_z    <<<gMM,  BS, 0, stream>>>(bufB, W2, b2, wc, zbuf, N);
    agg_scalar      <<<gN,   BS, 0, stream>>>(zbuf, ew, rowptr, dinv, wc, logits, N);
}

// Round 4
// 318.014 us; speedup vs baseline: 3.4483x; 1.1239x over previous
//
#include <hip/hip_runtime.h>

// GCN 3-layer, R4: latency-chain elimination.
//  a1 = S x (float4 {a1.xyz, dinv^2}), wave-per-node lane-per-edge gather.
//  pay[p] = {a1[src].xyz, w}  (edge-parallel gather, massive TLP)
//  fused_l2l3: wave-per-node streams pay -> a2 (lane=feat, h1 recomputed in-reg)
//              -> LDS exchange -> matmul with W2 column in VGPRs -> z scalar.
//  logits = S z + c, wave-per-node lane-per-edge (z gather is L2-resident 400KB).
// ws floats: dinv[N] | a1[4N] | rowptr[N+1] | bsums[1024] | ew[2E] | pay[4E] | z[N] | wc[65] | cnt[N] | fill[N]

__global__ void count_deg(const int* __restrict__ dst, int* __restrict__ cnt, int E) {
    int e = blockIdx.x * blockDim.x + threadIdx.x;
    if (e < E) atomicAdd(&cnt[dst[e]], 1);
}

__global__ void compute_dinv(const int* __restrict__ cnt, float* __restrict__ dinv, int N) {
    int n = blockIdx.x * blockDim.x + threadIdx.x;
    if (n < N) dinv[n] = rsqrtf((float)(cnt[n] + 1));   // +1 self-loop
}

// ---- exclusive scan cnt -> rowptr ----
__global__ void scan1(const int* __restrict__ cnt, int* __restrict__ rowptr,
                      int* __restrict__ bsums, int N) {
    __shared__ int tmp[256];
    int i = blockIdx.x * 256 + threadIdx.x;
    int v = (i < N) ? cnt[i] : 0;
    tmp[threadIdx.x] = v; __syncthreads();
    for (int off = 1; off < 256; off <<= 1) {
        int t = (threadIdx.x >= off) ? tmp[threadIdx.x - off] : 0;
        __syncthreads();
        tmp[threadIdx.x] += t;
        __syncthreads();
    }
    if (i < N) rowptr[i] = tmp[threadIdx.x] - v;
    if (threadIdx.x == 255) bsums[blockIdx.x] = tmp[255];
}

__global__ void scan2(int* __restrict__ bsums, int nb) {    // 1 block, 1024 thr
    __shared__ int tmp[1024];
    int v = (threadIdx.x < nb) ? bsums[threadIdx.x] : 0;
    tmp[threadIdx.x] = v; __syncthreads();
    for (int off = 1; off < 1024; off <<= 1) {
        int t = (threadIdx.x >= off) ? tmp[threadIdx.x - off] : 0;
        __syncthreads();
        tmp[threadIdx.x] += t;
        __syncthreads();
    }
    if (threadIdx.x < nb) bsums[threadIdx.x] = tmp[threadIdx.x] - v;
}

__global__ void scan3(int* __restrict__ rowptr, const int* __restrict__ bsums, int N, int E) {
    int i = blockIdx.x * 256 + threadIdx.x;
    if (i < N) rowptr[i] += bsums[blockIdx.x];
    if (i == 0) rowptr[N] = E;
}

__global__ void csr_fill(const int* __restrict__ src, const int* __restrict__ dst,
                         const float* __restrict__ dinv, const int* __restrict__ rowptr,
                         int* __restrict__ fill, float2* __restrict__ ew, int E) {
    int e = blockIdx.x * blockDim.x + threadIdx.x;
    if (e >= E) return;
    int s = src[e], d = dst[e];
    int p = rowptr[d] + atomicAdd(&fill[d], 1);
    ew[p] = make_float2(__int_as_float(s), dinv[s] * dinv[d]);
}

// a1[n] = {S x}[n], .w = dinv^2; wave per node, lane per edge, shuffle reduce
__global__ void agg3_wave(const float* __restrict__ x, const float2* __restrict__ ew,
                          const int* __restrict__ rowptr, const float* __restrict__ dinv,
                          float4* __restrict__ a1, int N) {
    int wid  = (blockIdx.x * blockDim.x + threadIdx.x) >> 6;
    int lane = threadIdx.x & 63;
    if (wid >= N) return;
    int p0 = rowptr[wid], p1 = rowptr[wid+1];
    float ax = 0.f, ay = 0.f, az = 0.f;
    for (int p = p0 + lane; p < p1; p += 64) {
        float2 e = ew[p];                       // coalesced
        int s = __float_as_int(e.x);
        float w = e.y;
        ax = fmaf(w, x[s*3+0], ax);             // 64 independent gathers in flight
        ay = fmaf(w, x[s*3+1], ay);
        az = fmaf(w, x[s*3+2], az);
    }
    #pragma unroll
    for (int off = 32; off; off >>= 1) {
        ax += __shfl_down(ax, off);
        ay += __shfl_down(ay, off);
        az += __shfl_down(az, off);
    }
    if (lane == 0) {
        float dv = dinv[wid], sw = dv * dv;
        a1[wid] = make_float4(fmaf(sw, x[wid*3+0], ax),
                              fmaf(sw, x[wid*3+1], ay),
                              fmaf(sw, x[wid*3+2], az), sw);
    }
}

// edge-parallel payload: pay[p] = {a1[src].xyz, w}
__global__ void gather_a1(const float2* __restrict__ ew, const float4* __restrict__ a1,
                          float4* __restrict__ pay, int E) {
    int p = blockIdx.x * blockDim.x + threadIdx.x;
    if (p >= E) return;
    float2 e = ew[p];
    float4 s = a1[__float_as_int(e.x)];
    pay[p] = make_float4(s.x, s.y, s.z, e.y);
}

// wc[k] = W3[k][:] @ Wh; wc[64] = b3 @ Wh + bh
__global__ void fold_head(const float* __restrict__ W3, const float* __restrict__ b3,
                          const float* __restrict__ Wh, const float* __restrict__ bh,
                          float* __restrict__ wc) {
    int k = threadIdx.x;              // 64
    float acc = 0.0f;
    for (int f = 0; f < 64; f++) acc += W3[k*64+f] * Wh[f];
    wc[k] = acc;
    if (k == 0) {
        float bb = bh[0];
        for (int f = 0; f < 64; f++) bb += b3[f] * Wh[f];
        wc[64] = bb;
    }
}

// z[n] = relu( (S relu(a1@W1+b1))[n] @ W2 + b2 ) @ wc
// wave per node (NPW nodes/wave); lane = feature; W1 col, b1, b2, wc, W2 col in regs.
__global__ void fused_l2l3(const float4* __restrict__ pay, const int* __restrict__ rowptr,
                           const float4* __restrict__ a1, const float* __restrict__ W1,
                           const float* __restrict__ b1, const float* __restrict__ W2,
                           const float* __restrict__ b2, const float* __restrict__ wc,
                           float* __restrict__ z, int N) {
    __shared__ float a2buf[4][64];
    int lane = threadIdx.x & 63;
    int wv   = threadIdx.x >> 6;
    float w10 = W1[lane], w11 = W1[64 + lane], w12 = W1[128 + lane], b1f = b1[lane];
    float b2f = b2[lane], wcf = wc[lane];
    float w2col[64];
    #pragma unroll
    for (int k = 0; k < 64; k++) w2col[k] = W2[k*64 + lane];   // coalesced, L1-hit
    const int NPW = 8;
    int n0 = (blockIdx.x * 4 + wv) * NPW;
    for (int i = 0; i < NPW; i++) {
        int n = n0 + i;
        if (n >= N) return;
        float4 an = a1[n];                                     // .w = dinv^2
        float t = fmaf(an.z, w12, fmaf(an.y, w11, fmaf(an.x, w10, b1f)));
        float acc = an.w * fmaxf(t, 0.f);
        int p = rowptr[n], pe = rowptr[n+1];
        for (; p + 3 < pe; p += 4) {                           // streaming, no addr chain
            float4 e0 = pay[p], e1 = pay[p+1], e2 = pay[p+2], e3 = pay[p+3];
            float t0 = fmaf(e0.z, w12, fmaf(e0.y, w11, fmaf(e0.x, w10, b1f)));
            float t1 = fmaf(e1.z, w12, fmaf(e1.y, w11, fmaf(e1.x, w10, b1f)));
            float t2 = fmaf(e2.z, w12, fmaf(e2.y, w11, fmaf(e2.x, w10, b1f)));
            float t3 = fmaf(e3.z, w12, fmaf(e3.y, w11, fmaf(e3.x, w10, b1f)));
            acc = fmaf(e0.w, fmaxf(t0, 0.f), acc);
            acc = fmaf(e1.w, fmaxf(t1, 0.f), acc);
            acc = fmaf(e2.w, fmaxf(t2, 0.f), acc);
            acc = fmaf(e3.w, fmaxf(t3, 0.f), acc);
        }
        for (; p < pe; ++p) {
            float4 e0 = pay[p];
            float t0 = fmaf(e0.z, w12, fmaf(e0.y, w11, fmaf(e0.x, w10, b1f)));
            acc = fmaf(e0.w, fmaxf(t0, 0.f), acc);
        }
        // cross-lane exchange of a2 (wave-local LDS RAW; in-order per wave)
        a2buf[wv][lane] = acc;
        float h = b2f;
        const float4* a4 = (const float4*)a2buf[wv];
        #pragma unroll
        for (int k4 = 0; k4 < 16; k4++) {
            float4 a = a4[k4];                                 // wave-uniform broadcast
            h = fmaf(a.x, w2col[4*k4+0], h);
            h = fmaf(a.y, w2col[4*k4+1], h);
            h = fmaf(a.z, w2col[4*k4+2], h);
            h = fmaf(a.w, w2col[4*k4+3], h);
        }
        float v = fmaxf(h, 0.f) * wcf;
        #pragma unroll
        for (int off = 32; off; off >>= 1) v += __shfl_down(v, off);
        if (lane == 0) z[n] = v;
    }
}

// logits[n] = dinv^2 z[n] + sum_e w z[s] + c; wave per node, lane per edge
__global__ void final_wave(const float* __restrict__ z, const float2* __restrict__ ew,
                           const int* __restrict__ rowptr, const float* __restrict__ dinv,
                           const float* __restrict__ wc, float* __restrict__ out, int N) {
    int wid  = (blockIdx.x * blockDim.x + threadIdx.x) >> 6;
    int lane = threadIdx.x & 63;
    if (wid >= N) return;
    int p0 = rowptr[wid], p1 = rowptr[wid+1];
    float acc = 0.f;
    for (int p = p0 + lane; p < p1; p += 64) {
        float2 e = ew[p];
        acc = fmaf(e.y, z[__float_as_int(e.x)], acc);   // 400KB z: L2-resident
    }
    #pragma unroll
    for (int off = 32; off; off >>= 1) acc += __shfl_down(acc, off);
    if (lane == 0) {
        float dv = dinv[wid];
        out[wid] = fmaf(dv * dv, z[wid], acc) + wc[64];
    }
}

extern "C" void kernel_launch(void* const* d_in, const int* in_sizes, int n_in,
                              void* d_out, int out_size, void* d_ws, size_t ws_size,
                              hipStream_t stream) {
    const float* x   = (const float*)d_in[0];
    const int*   ei  = (const int*)d_in[1];
    const float* W1  = (const float*)d_in[2];
    const float* b1  = (const float*)d_in[3];
    const float* W2  = (const float*)d_in[4];
    const float* b2  = (const float*)d_in[5];
    const float* W3  = (const float*)d_in[6];
    const float* b3  = (const float*)d_in[7];
    const float* Wh  = (const float*)d_in[8];
    const float* bh  = (const float*)d_in[9];
    float* logits = (float*)d_out;

    const int N = in_sizes[0] / 3;
    const int E = in_sizes[1] / 2;
    const int* src = ei;
    const int* dst = ei + E;

    float* base = (float*)d_ws;
    size_t o = 0;
    float*  dinv   = base + o; o += (size_t)N;
    o = (o + 3) & ~(size_t)3;
    float4* a1     = (float4*)(base + o); o += (size_t)4*N;
    int*    rowptr = (int*)(base + o); o += (size_t)N + 1;
    int*    bsums  = (int*)(base + o); o += 1024;
    o = (o + 1) & ~(size_t)1;
    float2* ew     = (float2*)(base + o); o += (size_t)2*E;
    o = (o + 3) & ~(size_t)3;
    float4* pay    = (float4*)(base + o); o += (size_t)4*E;
    float*  zbuf   = base + o; o += (size_t)N;
    float*  wc     = base + o; o += 65;
    int*    cnt    = (int*)(base + o); o += (size_t)N;
    int*    fill   = (int*)(base + o); o += (size_t)N;

    const int BS = 256;
    int gE   = (E + BS - 1) / BS;
    int gN   = (N + BS - 1) / BS;
    int gWN  = (N + 3) / 4;              // wave per node, 4 waves/block
    int gFU  = (N + 31) / 32;            // fused: 4 waves x 8 nodes per block

    hipMemsetAsync(cnt,  0, (size_t)N * sizeof(int), stream);
    hipMemsetAsync(fill, 0, (size_t)N * sizeof(int), stream);

    count_deg   <<<gE, BS, 0, stream>>>(dst, cnt, E);
    compute_dinv<<<gN, BS, 0, stream>>>(cnt, dinv, N);
    scan1       <<<gN, BS, 0, stream>>>(cnt, rowptr, bsums, N);
    scan2       <<<1, 1024, 0, stream>>>(bsums, gN);
    scan3       <<<gN, BS, 0, stream>>>(rowptr, bsums, N, E);
    csr_fill    <<<gE, BS, 0, stream>>>(src, dst, dinv, rowptr, fill, ew, E);

    agg3_wave   <<<gWN, BS, 0, stream>>>(x, ew, rowptr, dinv, a1, N);
    fold_head   <<<1, 64, 0, stream>>>(W3, b3, Wh, bh, wc);
    gather_a1   <<<gE,  BS, 0, stream>>>(ew, a1, pay, E);
    fused_l2l3  <<<gFU, BS, 0, stream>>>(pay, rowptr, a1, W1, b1, W2, b2, wc, zbuf, N);
    final_wave  <<<gWN, BS, 0, stream>>>(zbuf, ew, rowptr, dinv, wc, logits, N);
}